// Round 8
// baseline (95.698 us; speedup 1.0000x reference)
//
#include <hip/hip_runtime.h>
#include <cstdint>
#include <cstddef>

#define T_N    32768
#define N_SEG  2048
#define DSEQ   128
#define DLSTM  512
#define DX     512
#define DPROJ  1024
#define OUTW   2048
#define WSCALE 2873.6827f                 // 127*sqrt(512)
#define LOG2E2 2.8853900817779268f        // 2*log2(e)
#define DEQ2   (2.8853900817779268f/(2873.6827f*127.0f))
#define MAGIC_C (12582912.0f + 127.0f)    // 1.5*2^23 + 127 (fused RNE-round const)

typedef __attribute__((ext_vector_type(8))) short short8;
typedef __attribute__((ext_vector_type(4))) float f32x4;
typedef __attribute__((ext_vector_type(4))) int i32x4;

#if __has_builtin(__builtin_amdgcn_exp2f)
#define EXP2F(x) __builtin_amdgcn_exp2f(x)
#else
#define EXP2F(x) __expf((x) * 0.6931471805599453f)
#endif
#if __has_builtin(__builtin_amdgcn_rcpf)
#define RCPF(x) __builtin_amdgcn_rcpf(x)
#else
#define RCPF(x) (1.0f / (x))
#endif

__device__ inline unsigned short f2b(float f) {
  unsigned int u = __float_as_uint(f);
  unsigned int r = (u + 0x7FFFu + ((u >> 16) & 1u)) >> 16;
  return (unsigned short)r;
}
__device__ inline unsigned int cvtpk(float a, float b) {
  unsigned int r;
  asm("v_cvt_pk_bf16_f32 %0, %1, %2" : "=v"(r) : "v"(a), "v"(b));
  return r;
}

// ---------------- prep: seg bounds + permuted i8 W_hh frag pack + bf16 W_ih frag pack ----------------
// blocks [0,128): bounds. [128,256): W8. [256,272): WF.
// W8 frag id = (((dir*16 + wv)*2 + mt)*8 + kt)*64 + lane (16B each)
//   row rr = lane&15 -> dim n = wv*32 + mt*4 + (rr&3) + (rr>>2)*8 ; k = kt*64 + (lane>>4)*16 + j
__global__ void prep_kernel(const int* __restrict__ masks,
                            int* __restrict__ seg_start, int* __restrict__ seg_end,
                            const float* __restrict__ Whh_f, const float* __restrict__ Whh_b,
                            const float* __restrict__ Wih_f, const float* __restrict__ Wih_b,
                            signed char* __restrict__ W8, unsigned short* __restrict__ WF) {
  const int bx = blockIdx.x;
  if (bx < T_N / 256) {
    int t = bx * 256 + threadIdx.x;
    int m = masks[t];
    if (t == 0 || masks[t - 1] != m) seg_start[m] = t;
    if (t == T_N - 1 || masks[t + 1] != m) seg_end[m] = t + 1;
  } else if (bx < T_N / 256 + 128) {
    int id = (bx - T_N / 256) * 256 + threadIdx.x;   // < 32768
    int dir = id >> 14;
    int rem = id & 16383;
    int wv = rem >> 10;
    int mt = (rem >> 9) & 1;
    int kt = (rem >> 6) & 7;
    int lane = rem & 63;
    int rr = lane & 15;
    int n = wv * 32 + mt * 4 + (rr & 3) + (rr >> 2) * 8;
    int k0 = kt * 64 + (lane >> 4) * 16;
    const float* W = dir ? Whh_b : Whh_f;
    signed char pkt[16];
#pragma unroll
    for (int j = 0; j < 16; ++j) {
      float w = W[(size_t)n * DLSTM + k0 + j];
      int q = (int)rintf(w * WSCALE);
      q = q > 127 ? 127 : (q < -127 ? -127 : q);
      pkt[j] = (signed char)q;
    }
    i32x4 v;
    __builtin_memcpy(&v, pkt, 16);
    *(i32x4*)&W8[(size_t)id * 16] = v;
  } else {
    // WF: A-frag packed [g(64)][lane(64)][kt(4)][8 bf16]
    int gl = (bx - (T_N / 256 + 128)) * 256 + threadIdx.x;   // < 4096
    int g = gl >> 6, lane = gl & 63;
    int n = g * 16 + (lane & 15);
    const float* src = (n < 512) ? (Wih_f + (size_t)n * DSEQ)
                                 : (Wih_b + (size_t)(n - 512) * DSEQ);
#pragma unroll
    for (int kt = 0; kt < 4; ++kt) {
      int k0 = kt * 32 + (lane >> 4) * 8;
      float4 v0 = *(const float4*)(src + k0);
      float4 v1 = *(const float4*)(src + k0 + 4);
      unsigned int w[4] = {cvtpk(v0.x, v0.y), cvtpk(v0.z, v0.w),
                           cvtpk(v1.x, v1.y), cvtpk(v1.z, v1.w)};
      *(uint4*)&WF[(size_t)((gl << 2) + kt) * 8] = *(uint4*)w;
    }
  }
}

// ---------------- combo kernel (256 thr): bid 0 = csort, 1..128 = proj GEMM, 129..640 = pre-GEMM ----------------
__global__ __launch_bounds__(256, 2) void combo_kernel(
    const int* __restrict__ seg_start, const int* __restrict__ seg_end,
    int* __restrict__ sorted_ids,
    const float* __restrict__ x, const float* __restrict__ Wx,
    const float* __restrict__ bx, float* __restrict__ out,
    const float* __restrict__ seqs, const unsigned short* __restrict__ WF,
    const float* __restrict__ b_f, const float* __restrict__ b_b,
    unsigned short* __restrict__ pre) {
  __shared__ __align__(16) char smem[20608];
  const int bid = blockIdx.x;
  const int tid = threadIdx.x;

  if (bid == 0) {
    // ---------- counting sort by length, descending (256 threads) ----------
    int* A_ = (int*)smem;
    int* B_ = A_ + 2048;
    for (int i = tid; i < 2048; i += 256) A_[i] = 0;
    __syncthreads();
    for (int i = tid; i < N_SEG; i += 256) {
      int len = seg_end[i] - seg_start[i];
      int b = len < 2047 ? len : 2047;
      atomicAdd(&A_[b], 1);
    }
    __syncthreads();
    int* src = A_;
    int* dst = B_;
    for (int d = 1; d < 2048; d <<= 1) {
      for (int i = tid; i < 2048; i += 256) {
        int v = src[i];
        if (i + d < 2048) v += src[i + d];
        dst[i] = v;
      }
      __syncthreads();
      int* t_ = src; src = dst; dst = t_;
    }
    for (int i = tid; i < 2048; i += 256)
      dst[i] = (i + 1 < 2048) ? src[i + 1] : 0;
    __syncthreads();
    for (int i = tid; i < N_SEG; i += 256) {
      int len = seg_end[i] - seg_start[i];
      int b = len < 2047 ? len : 2047;
      int pos = atomicAdd(&dst[b], 1);
      sorted_ids[pos] = i;
    }
  } else if (bid <= 128) {
    // ---------- proj GEMM: out[:,0:1024] = x @ Wx^T + bx (128x128 tile) ----------
    const int pb_ = bid - 1;
    const int m0 = (pb_ >> 3) * 128, n0 = (pb_ & 7) * 128;
    unsigned short (*As)[40] = (unsigned short(*)[40])smem;
    unsigned short (*Bs)[40] = (unsigned short(*)[40])(smem + 10240);
    const int wave = tid >> 6, lane = tid & 63;
    const int wm = (wave >> 1) * 64, wn = (wave & 1) * 64;
    const int rowA = lane & 15, kgrp = lane >> 4;
    const int lrow = tid >> 1, lkc = (tid & 1) * 16;

    f32x4 acc[4][4];
#pragma unroll
    for (int i = 0; i < 4; ++i)
#pragma unroll
      for (int j = 0; j < 4; ++j) acc[i][j] = (f32x4){0.f, 0.f, 0.f, 0.f};

    for (int k0 = 0; k0 < DX; k0 += 32) {
      __syncthreads();
      {
        const float* ap = x + (size_t)(m0 + lrow) * DX + k0 + lkc;
        unsigned short pa[16];
#pragma unroll
        for (int q = 0; q < 4; ++q) {
          float4 v = *(const float4*)(ap + q * 4);
          pa[q * 4 + 0] = f2b(v.x); pa[q * 4 + 1] = f2b(v.y);
          pa[q * 4 + 2] = f2b(v.z); pa[q * 4 + 3] = f2b(v.w);
        }
        *(short8*)&As[lrow][lkc] = *(short8*)&pa[0];
        *(short8*)&As[lrow][lkc + 8] = *(short8*)&pa[8];

        const float* bp = Wx + (size_t)(n0 + lrow) * DX + k0 + lkc;
        unsigned short pb2[16];
#pragma unroll
        for (int q = 0; q < 4; ++q) {
          float4 v = *(const float4*)(bp + q * 4);
          pb2[q * 4 + 0] = f2b(v.x); pb2[q * 4 + 1] = f2b(v.y);
          pb2[q * 4 + 2] = f2b(v.z); pb2[q * 4 + 3] = f2b(v.w);
        }
        *(short8*)&Bs[lrow][lkc] = *(short8*)&pb2[0];
        *(short8*)&Bs[lrow][lkc + 8] = *(short8*)&pb2[8];
      }
      __syncthreads();
      short8 af[4], bf[4];
#pragma unroll
      for (int mt = 0; mt < 4; ++mt) af[mt] = *(const short8*)&As[wm + mt * 16 + rowA][kgrp * 8];
#pragma unroll
      for (int nt = 0; nt < 4; ++nt) bf[nt] = *(const short8*)&Bs[wn + nt * 16 + rowA][kgrp * 8];
#pragma unroll
      for (int mt = 0; mt < 4; ++mt)
#pragma unroll
        for (int nt = 0; nt < 4; ++nt)
          acc[mt][nt] = __builtin_amdgcn_mfma_f32_16x16x32_bf16(af[mt], bf[nt], acc[mt][nt], 0, 0, 0);
    }

#pragma unroll
    for (int mt = 0; mt < 4; ++mt)
#pragma unroll
      for (int nt = 0; nt < 4; ++nt) {
        int n = n0 + wn + nt * 16 + rowA;
        float bv = bx[n];
#pragma unroll
        for (int r = 0; r < 4; ++r) {
          int m = m0 + wm + mt * 16 + kgrp * 4 + r;
          out[(size_t)m * OUTW + n] = acc[mt][nt][r] + bv;
        }
      }
  } else {
    // ---------- pre-GEMM (operand-swapped, LDS-free) ----------
    const int m0 = (bid - 129) * 64;
    const int wave = tid >> 6, lane = tid & 63;
    const int kgrp = lane >> 4;

    short8 bfr[4][4];
#pragma unroll
    for (int mt = 0; mt < 4; ++mt) {
      const float* sp = seqs + (size_t)(m0 + mt * 16 + (lane & 15)) * DSEQ;
#pragma unroll
      for (int kt = 0; kt < 4; ++kt) {
        int k0 = kt * 32 + kgrp * 8;
        float4 v0 = *(const float4*)(sp + k0);
        float4 v1 = *(const float4*)(sp + k0 + 4);
        unsigned int w[4] = {cvtpk(v0.x, v0.y), cvtpk(v0.z, v0.w),
                             cvtpk(v1.x, v1.y), cvtpk(v1.z, v1.w)};
        bfr[mt][kt] = *(short8*)w;
      }
    }

#pragma unroll
    for (int pass = 0; pass < 2; ++pass) {
      f32x4 acc[8][4];
#pragma unroll
      for (int nf = 0; nf < 8; ++nf)
#pragma unroll
        for (int mt = 0; mt < 4; ++mt) acc[nf][mt] = (f32x4){0.f, 0.f, 0.f, 0.f};

#pragma unroll
      for (int nf = 0; nf < 8; ++nf) {
        const int g = wave * 16 + pass * 8 + nf;
        short8 wf[4];
        const unsigned short* wp = WF + (size_t)((g * 64 + lane) << 2) * 8;
#pragma unroll
        for (int kt = 0; kt < 4; ++kt) wf[kt] = *(const short8*)(wp + kt * 8);
#pragma unroll
        for (int kt = 0; kt < 4; ++kt)
#pragma unroll
          for (int mt = 0; mt < 4; ++mt)
            acc[nf][mt] = __builtin_amdgcn_mfma_f32_16x16x32_bf16(wf[kt], bfr[mt][kt],
                                                                  acc[nf][mt], 0, 0, 0);
      }

#pragma unroll
      for (int nf = 0; nf < 8; ++nf) {
        const int g = wave * 16 + pass * 8 + nf;
        const float* bsrc = (g < 32) ? (b_f + g * 16) : (b_b + (g - 32) * 16);
        float4 bv = *(const float4*)(bsrc + kgrp * 4);
        float bs[4] = {bv.x * LOG2E2, bv.y * LOG2E2, bv.z * LOG2E2, bv.w * LOG2E2};
#pragma unroll
        for (int mt = 0; mt < 4; ++mt) {
          float v0 = fmaf(acc[nf][mt][0], LOG2E2, bs[0]);
          float v1 = fmaf(acc[nf][mt][1], LOG2E2, bs[1]);
          float v2 = fmaf(acc[nf][mt][2], LOG2E2, bs[2]);
          float v3 = fmaf(acc[nf][mt][3], LOG2E2, bs[3]);
          unsigned int w[2] = {cvtpk(v0, v1), cvtpk(v2, v3)};
          size_t m = (size_t)(m0 + mt * 16 + (lane & 15));
          *(uint2*)&pre[m * 1024 + g * 16 + kgrp * 4] = *(uint2*)w;
        }
      }
    }
  }
}

// ---------------- scan: 16 waves/block, 32 dims/wave, weights register-resident ----------------
// grid 256 (batch = bid>>1, dir = bid&1), block 1024.
// Thread dims: dbase(wv*32) + kgrp*8 + mt*4 + r  (8 consecutive dims).
__global__ __launch_bounds__(1024, 4) void scan_kernel(
    const unsigned short* __restrict__ pre,   // [T][1024] bf16, pre-scaled by 2*log2(e)
    const signed char* __restrict__ W8,
    const int* __restrict__ sorted_ids, const int* __restrict__ seg_start_g,
    const int* __restrict__ seg_end_g, float* __restrict__ out) {
  const int dir = blockIdx.x & 1, bb = blockIdx.x >> 1;
  const int tid = threadIdx.x;
  const int wv = tid >> 6, lane = tid & 63;
  const int chain = lane & 15, kgrp = lane >> 4;
  const int dbase = wv * 32;

  __shared__ __align__(16) signed char Hs[2 * 16 * 528];
  __shared__ int s_start[16], s_len[16], s_sid[16];

  if (tid < 16) {
    int sid = sorted_ids[bb * 16 + tid];
    s_sid[tid] = sid;
    int st = seg_start_g[sid];
    s_start[tid] = st;
    s_len[tid] = seg_end_g[sid] - st;
  }
  {  // zero H[0]: 16 rows x 512B, 8B/thread
    int r = tid >> 6, o = (tid & 63) * 8;
    *(uint2*)&Hs[r * 528 + o] = make_uint2(0u, 0u);
  }

  // weights: 2 mt x 8 kt frags of 16B -> 64 VGPR
  i32x4 w0[8], w1[8];
  {
    const signed char* wb = W8 + (((size_t)(dir * 16 + wv)) << 14) + (size_t)lane * 16;
#pragma unroll
    for (int kt = 0; kt < 8; ++kt) {
      w0[kt] = *(const i32x4*)(wb + kt * 1024);
      w1[kt] = *(const i32x4*)(wb + 8192 + kt * 1024);
    }
  }
  __syncthreads();

  const int maxlen = s_len[0];   // globally sorted desc -> first is batch max
  const int myLen = s_len[chain], myStart = s_start[chain];
  const int sid = s_sid[chain];

  const unsigned short* __restrict__ pbp = pre + (size_t)dir * 512 + dbase + kgrp * 8;

  uint4 pu0;
  {
    int t = dir ? (myStart + myLen - 1) : myStart;
    pu0 = *(const uint4*)(pbp + (size_t)t * 1024);
  }

  float pool0[4] = {0.f, 0.f, 0.f, 0.f};
  float pool1[4] = {0.f, 0.f, 0.f, 0.f};

  int cur = 0;
  for (int s = 0; s < maxlen; ++s) {
    // prefetch pre for step s+1 (stays in flight across the raw barrier)
    uint4 puN;
    {
      int sn = (s + 1 < myLen) ? (s + 1) : (myLen - 1);
      int t = dir ? (myStart + myLen - 1 - sn) : (myStart + sn);
      puN = *(const uint4*)(pbp + (size_t)t * 1024);
    }

    i32x4 acc0 = (i32x4){0, 0, 0, 0}, acc1 = (i32x4){0, 0, 0, 0};
    const signed char* hrow = Hs + cur * 8448 + chain * 528;
#pragma unroll
    for (int kt = 0; kt < 8; ++kt) {
      i32x4 hb = *(const i32x4*)(hrow + kt * 64 + kgrp * 16);
      acc0 = __builtin_amdgcn_mfma_i32_16x16x64_i8(w0[kt], hb, acc0, 0, 0, 0);
      acc1 = __builtin_amdgcn_mfma_i32_16x16x64_i8(w1[kt], hb, acc1, 0, 0, 0);
    }

    const float msk = (s < myLen) ? 1.f : 0.f;
    unsigned int pk0, pk1;
    {
      float p2[4];
      p2[0] = __uint_as_float(pu0.x << 16);
      p2[1] = __uint_as_float(pu0.x & 0xFFFF0000u);
      p2[2] = __uint_as_float(pu0.y << 16);
      p2[3] = __uint_as_float(pu0.y & 0xFFFF0000u);
      unsigned int b[4];
#pragma unroll
      for (int r = 0; r < 4; ++r) {
        float x2 = fmaf((float)acc0[r], DEQ2, p2[r]);
        float e = EXP2F(x2);
        float rc = RCPF(e + 1.f);
        pool0[r] = fmaf(rc, msk, pool0[r]);
        b[r] = __float_as_uint(fmaf(-254.f, rc, MAGIC_C));
      }
      pk0 = (b[0] & 255u) | ((b[1] & 255u) << 8) | ((b[2] & 255u) << 16) | (b[3] << 24);
    }
    {
      float p2[4];
      p2[0] = __uint_as_float(pu0.z << 16);
      p2[1] = __uint_as_float(pu0.z & 0xFFFF0000u);
      p2[2] = __uint_as_float(pu0.w << 16);
      p2[3] = __uint_as_float(pu0.w & 0xFFFF0000u);
      unsigned int b[4];
#pragma unroll
      for (int r = 0; r < 4; ++r) {
        float x2 = fmaf((float)acc1[r], DEQ2, p2[r]);
        float e = EXP2F(x2);
        float rc = RCPF(e + 1.f);
        pool1[r] = fmaf(rc, msk, pool1[r]);
        b[r] = __float_as_uint(fmaf(-254.f, rc, MAGIC_C));
      }
      pk1 = (b[0] & 255u) | ((b[1] & 255u) << 8) | ((b[2] & 255u) << 16) | (b[3] << 24);
    }
    *(uint2*)(Hs + (cur ^ 1) * 8448 + chain * 528 + dbase + kgrp * 8) = make_uint2(pk0, pk1);

    asm volatile("s_waitcnt lgkmcnt(0)" ::: "memory");
    __builtin_amdgcn_s_barrier();
    __builtin_amdgcn_sched_barrier(0);
    pu0 = puN;
    cur ^= 1;
  }

  // mean(h) = 1 - 2*sum(rc)/len
  const float s2 = -2.0f / (float)myLen;
  float* op = out + (size_t)sid * OUTW + DPROJ + dir * DLSTM + dbase + kgrp * 8;
  *(float4*)op = make_float4(fmaf(s2, pool0[0], 1.f), fmaf(s2, pool0[1], 1.f),
                             fmaf(s2, pool0[2], 1.f), fmaf(s2, pool0[3], 1.f));
  *(float4*)(op + 4) = make_float4(fmaf(s2, pool1[0], 1.f), fmaf(s2, pool1[1], 1.f),
                                   fmaf(s2, pool1[2], 1.f), fmaf(s2, pool1[3], 1.f));
}

extern "C" void kernel_launch(void* const* d_in, const int* in_sizes, int n_in,
                              void* d_out, int out_size, void* d_ws, size_t ws_size,
                              hipStream_t stream) {
  const float* x     = (const float*)d_in[0];
  const float* seqs  = (const float*)d_in[1];
  const int*   masks = (const int*)d_in[2];
  const float* Wih_f = (const float*)d_in[3];
  const float* Whh_f = (const float*)d_in[4];
  const float* b_f   = (const float*)d_in[5];
  const float* Wih_b = (const float*)d_in[6];
  const float* Whh_b = (const float*)d_in[7];
  const float* b_b   = (const float*)d_in[8];
  const float* Wx    = (const float*)d_in[9];
  const float* bx    = (const float*)d_in[10];
  float* out = (float*)d_out;

  char* ws = (char*)d_ws;
  const size_t pre_bytes = (size_t)T_N * 1024 * 2;   // 67.1 MB
  const size_t w8_bytes  = (size_t)2 * 512 * 512;    // 0.5 MB
  const size_t wf_bytes  = (size_t)1024 * 128 * 2;   // 256 KB
  unsigned short* pre = (unsigned short*)ws;
  signed char* W8     = (signed char*)(ws + pre_bytes);
  unsigned short* WF  = (unsigned short*)(ws + pre_bytes + w8_bytes);
  int* seg_start      = (int*)(ws + pre_bytes + w8_bytes + wf_bytes);
  int* seg_end        = seg_start + N_SEG;
  int* sorted_ids     = seg_end + N_SEG;

  prep_kernel<<<T_N / 256 + 128 + 16, 256, 0, stream>>>(
      masks, seg_start, seg_end, Whh_f, Whh_b, Wih_f, Wih_b, W8, WF);
  combo_kernel<<<641, 256, 0, stream>>>(
      seg_start, seg_end, sorted_ids, x, Wx, bx, out, seqs, WF, b_f, b_b, pre);
  scan_kernel<<<256, 1024, 0, stream>>>(
      pre, W8, sorted_ids, seg_start, seg_end, out);
}

// Round 9
// 90.024 us; speedup vs baseline: 1.0630x; 1.0630x over previous
//
#include <hip/hip_runtime.h>
#include <cstdint>
#include <cstddef>

#define T_N    32768
#define N_SEG  2048
#define DSEQ   128
#define DLSTM  512
#define DX     512
#define DPROJ  1024
#define OUTW   2048
#define WSCALE 2873.6827f                 // 127*sqrt(512)
#define SXQ    23.0909090909f             // 127/5.5 (x clip at +-5.5 sigma)
#define LOG2E2 2.8853900817779268f        // 2*log2(e)
#define DEQH   (2.8853900817779268f/(2873.6827f*127.0f))
#define DEQX   (2.8853900817779268f/(2873.6827f*23.0909090909f))
#define MAGICF 12582912.0f                // 1.5*2^23 RNE round-to-int trick
#define MAGIC_C (12582912.0f + 127.0f)

typedef __attribute__((ext_vector_type(8))) short short8;
typedef __attribute__((ext_vector_type(4))) float f32x4;
typedef __attribute__((ext_vector_type(4))) int i32x4;

#if __has_builtin(__builtin_amdgcn_exp2f)
#define EXP2F(x) __builtin_amdgcn_exp2f(x)
#else
#define EXP2F(x) __expf((x) * 0.6931471805599453f)
#endif
#if __has_builtin(__builtin_amdgcn_rcpf)
#define RCPF(x) __builtin_amdgcn_rcpf(x)
#else
#define RCPF(x) (1.0f / (x))
#endif

__device__ inline unsigned int cvtpk(float a, float b) {
  unsigned int r;
  asm("v_cvt_pk_bf16_f32 %0, %1, %2" : "=v"(r) : "v"(a), "v"(b));
  return r;
}

// ================= launch 1: prep =================
// bid 0: seg bounds + counting sort (desc) -> s_sid/s_st/s_ln
// bid 1..32: W_hh i8 frag pack (permuted rows, K=64 frags)
// bid 33..40: W_ih i8 frag pack (same permutation, K=128 -> 2 kt)
__global__ __launch_bounds__(1024) void prep_kernel(
    const int* __restrict__ masks,
    const float* __restrict__ Whh_f, const float* __restrict__ Whh_b,
    const float* __restrict__ Wih_f, const float* __restrict__ Wih_b,
    signed char* __restrict__ W8, signed char* __restrict__ WX8,
    int* __restrict__ s_sid, int* __restrict__ s_st, int* __restrict__ s_ln) {
  const int bid = blockIdx.x, tid = threadIdx.x;
  if (bid == 0) {
    __shared__ int st_l[2048], en_l[2048], A_[2048], B_[2048];
    for (int i = tid; i < 2048; i += 1024) A_[i] = 0;
    for (int t = tid; t < T_N; t += 1024) {
      int m = masks[t];
      if (t == 0 || masks[t - 1] != m) st_l[m] = t;
      if (t == T_N - 1 || masks[t + 1] != m) en_l[m] = t + 1;
    }
    __syncthreads();
    for (int i = tid; i < 2048; i += 1024) {
      int len = en_l[i] - st_l[i];
      atomicAdd(&A_[len < 2047 ? len : 2047], 1);
    }
    __syncthreads();
    int* src = A_;
    int* dst = B_;
    for (int d = 1; d < 2048; d <<= 1) {
      for (int i = tid; i < 2048; i += 1024) {
        int v = src[i];
        if (i + d < 2048) v += src[i + d];
        dst[i] = v;
      }
      __syncthreads();
      int* tp = src; src = dst; dst = tp;
    }
    for (int i = tid; i < 2048; i += 1024)
      dst[i] = (i + 1 < 2048) ? src[i + 1] : 0;
    __syncthreads();
    for (int i = tid; i < 2048; i += 1024) {
      int len = en_l[i] - st_l[i];
      int b = len < 2047 ? len : 2047;
      int pos = atomicAdd(&dst[b], 1);
      s_sid[pos] = i;
      s_st[pos] = st_l[i];
      s_ln[pos] = len;
    }
  } else if (bid <= 32) {
    // id = (((dir*16+wv)*2+mt)*8+kt)*64+lane ; n = wv*32+mt*4+(rr&3)+(rr>>2)*8
    int id = (bid - 1) * 1024 + tid;   // < 32768
    int dir = id >> 14;
    int rem = id & 16383;
    int wv = rem >> 10;
    int mt = (rem >> 9) & 1;
    int kt = (rem >> 6) & 7;
    int lane = rem & 63;
    int rr = lane & 15;
    int n = wv * 32 + mt * 4 + (rr & 3) + (rr >> 2) * 8;
    int k0 = kt * 64 + (lane >> 4) * 16;
    const float* W = dir ? Whh_b : Whh_f;
    const float* wp = W + (size_t)n * DLSTM + k0;
    signed char pkt[16];
#pragma unroll
    for (int q = 0; q < 4; ++q) {
      float4 v = *(const float4*)(wp + q * 4);
      float vv[4] = {v.x, v.y, v.z, v.w};
#pragma unroll
      for (int j = 0; j < 4; ++j) {
        int qq = (int)rintf(vv[j] * WSCALE);
        qq = qq > 127 ? 127 : (qq < -127 ? -127 : qq);
        pkt[q * 4 + j] = (signed char)qq;
      }
    }
    i32x4 v16;
    __builtin_memcpy(&v16, pkt, 16);
    *(i32x4*)&W8[(size_t)id * 16] = v16;
  } else {
    // id = (((dir*16+wv)*2+mt)*2+kt)*64+lane ; k in [0,128)
    int id = (bid - 33) * 1024 + tid;  // < 8192
    int dir = id >> 12;
    int rem = id & 4095;
    int wv = rem >> 8;
    int mt = (rem >> 7) & 1;
    int kt = (rem >> 6) & 1;
    int lane = rem & 63;
    int rr = lane & 15;
    int n = wv * 32 + mt * 4 + (rr & 3) + (rr >> 2) * 8;
    int k0 = kt * 64 + (lane >> 4) * 16;
    const float* W = dir ? Wih_b : Wih_f;
    const float* wp = W + (size_t)n * DSEQ + k0;
    signed char pkt[16];
#pragma unroll
    for (int q = 0; q < 4; ++q) {
      float4 v = *(const float4*)(wp + q * 4);
      float vv[4] = {v.x, v.y, v.z, v.w};
#pragma unroll
      for (int j = 0; j < 4; ++j) {
        int qq = (int)rintf(vv[j] * WSCALE);
        qq = qq > 127 ? 127 : (qq < -127 ? -127 : qq);
        pkt[q * 4 + j] = (signed char)qq;
      }
    }
    i32x4 v16;
    __builtin_memcpy(&v16, pkt, 16);
    *(i32x4*)&WX8[(size_t)id * 16] = v16;
  }
}

// ================= launch 2: fused scan (+input proj) + tail proj GEMM =================
// grid 256, block 1024 (16 waves). All blocks: scan of (batch=bid>>1, dir=bid&1).
// Blocks >=128 (short batches, finish early) then do one 128x128 proj tile.
__global__ __launch_bounds__(1024) void fused_kernel(
    const float* __restrict__ seqs,
    const signed char* __restrict__ W8, const signed char* __restrict__ WX8,
    const int* __restrict__ s_sid_g, const int* __restrict__ s_st_g,
    const int* __restrict__ s_ln_g,
    const float* __restrict__ b_f, const float* __restrict__ b_b,
    const float* __restrict__ x, const float* __restrict__ Wx,
    const float* __restrict__ bx, float* __restrict__ out) {
  __shared__ __align__(16) char smem[21760];
  const int bid = blockIdx.x, tid = threadIdx.x;
  const int wv = tid >> 6, lane = tid & 63;

  // ---------------- scan phase ----------------
  {
    const int dir = bid & 1, bb = bid >> 1;
    const int chain = lane & 15, kgrp = lane >> 4;
    const int dbase = wv << 5;
    signed char* H = (signed char*)smem;             // [2][16][528]
    signed char* Xs = (signed char*)(smem + 16896);  // [2][16][144]
    int* meta = (int*)(smem + 21504);                // sid[16] | st[16] | ln[16]

    if (tid < 16) {
      meta[tid] = s_sid_g[bb * 16 + tid];
      meta[16 + tid] = s_st_g[bb * 16 + tid];
      meta[32 + tid] = s_ln_g[bb * 16 + tid];
    }
    {  // zero H[0]
      int r = tid >> 6, o = (lane) << 3;
      *(uint2*)(H + r * 528 + o) = make_uint2(0u, 0u);
    }

    // register-resident weights: W_hh 32 frags (128B->32 regs? 8x16B x2 = 64 VGPR), W_ih 4 frags (16 VGPR)
    i32x4 w0[8], w1[8], wx0[2], wx1[2];
    {
      const signed char* wb = W8 + ((size_t)((dir << 4) + wv) << 14) + (lane << 4);
#pragma unroll
      for (int kt = 0; kt < 8; ++kt) {
        w0[kt] = *(const i32x4*)(wb + kt * 1024);
        w1[kt] = *(const i32x4*)(wb + 8192 + kt * 1024);
      }
      const signed char* wxb = WX8 + ((size_t)((dir << 4) + wv) << 12) + (lane << 4);
      wx0[0] = *(const i32x4*)(wxb);
      wx0[1] = *(const i32x4*)(wxb + 1024);
      wx1[0] = *(const i32x4*)(wxb + 2048);
      wx1[1] = *(const i32x4*)(wxb + 3072);
    }
    float bsc[8];
    {
      const float* bp = (dir ? b_b : b_f) + dbase + (kgrp << 3);
      float4 u0 = *(const float4*)bp;
      float4 u1 = *(const float4*)(bp + 4);
      bsc[0] = u0.x * LOG2E2; bsc[1] = u0.y * LOG2E2;
      bsc[2] = u0.z * LOG2E2; bsc[3] = u0.w * LOG2E2;
      bsc[4] = u1.x * LOG2E2; bsc[5] = u1.y * LOG2E2;
      bsc[6] = u1.z * LOG2E2; bsc[7] = u1.w * LOG2E2;
    }
    __syncthreads();

    const int myLen = meta[32 + chain];
    const int stStart = meta[16 + wv], stLen = meta[32 + wv];
    const int maxlen = meta[32];  // globally sorted desc -> batch max

    // prologue: stage x(0) as i8 (wave wv stages chain wv; 64 lanes x 2 floats)
    {
      int t0 = dir ? (stStart + stLen - 1) : stStart;
      float2 xv0 = *(const float2*)(seqs + (size_t)t0 * DSEQ + (lane << 1));
      unsigned c0 = __float_as_uint(fminf(fmaxf(xv0.x * SXQ, -127.f), 127.f) + MAGICF);
      unsigned c1 = __float_as_uint(fminf(fmaxf(xv0.y * SXQ, -127.f), 127.f) + MAGICF);
      *(unsigned short*)(Xs + wv * 144 + (lane << 1)) =
          (unsigned short)((c0 & 255u) | ((c1 & 255u) << 8));
    }
    __syncthreads();

    float pool0[4] = {0.f, 0.f, 0.f, 0.f};
    float pool1[4] = {0.f, 0.f, 0.f, 0.f};

    int cur = 0;
    for (int s = 0; s < maxlen; ++s) {
      // issue next-step x load early (consumed at bottom of this body)
      int sn = (s + 1 < stLen) ? (s + 1) : (stLen - 1);
      int tn = dir ? (stStart + stLen - 1 - sn) : (stStart + sn);
      float2 xv = *(const float2*)(seqs + (size_t)tn * DSEQ + (lane << 1));

      i32x4 acc0 = (i32x4){0, 0, 0, 0}, acc1 = (i32x4){0, 0, 0, 0};
      i32x4 ax0 = (i32x4){0, 0, 0, 0}, ax1 = (i32x4){0, 0, 0, 0};
      {
        const signed char* xr = Xs + cur * 2304 + chain * 144;
#pragma unroll
        for (int kt = 0; kt < 2; ++kt) {
          i32x4 xb = *(const i32x4*)(xr + kt * 64 + (kgrp << 4));
          ax0 = __builtin_amdgcn_mfma_i32_16x16x64_i8(wx0[kt], xb, ax0, 0, 0, 0);
          ax1 = __builtin_amdgcn_mfma_i32_16x16x64_i8(wx1[kt], xb, ax1, 0, 0, 0);
        }
        const signed char* hr = H + cur * 8448 + chain * 528;
#pragma unroll
        for (int kt = 0; kt < 8; ++kt) {
          i32x4 hb = *(const i32x4*)(hr + kt * 64 + (kgrp << 4));
          acc0 = __builtin_amdgcn_mfma_i32_16x16x64_i8(w0[kt], hb, acc0, 0, 0, 0);
          acc1 = __builtin_amdgcn_mfma_i32_16x16x64_i8(w1[kt], hb, acc1, 0, 0, 0);
        }
      }

      const float msk = (s < myLen) ? 1.f : 0.f;
      unsigned pk0, pk1;
      {
        unsigned b[4];
#pragma unroll
        for (int r = 0; r < 4; ++r) {
          float x2 = fmaf((float)acc0[r], DEQH, fmaf((float)ax0[r], DEQX, bsc[r]));
          float e = EXP2F(x2);
          float rc = RCPF(e + 1.f);
          pool0[r] = fmaf(rc, msk, pool0[r]);
          b[r] = __float_as_uint(fmaf(-254.f, rc, MAGIC_C));
        }
        pk0 = (b[0] & 255u) | ((b[1] & 255u) << 8) | ((b[2] & 255u) << 16) | (b[3] << 24);
      }
      {
        unsigned b[4];
#pragma unroll
        for (int r = 0; r < 4; ++r) {
          float x2 = fmaf((float)acc1[r], DEQH, fmaf((float)ax1[r], DEQX, bsc[4 + r]));
          float e = EXP2F(x2);
          float rc = RCPF(e + 1.f);
          pool1[r] = fmaf(rc, msk, pool1[r]);
          b[r] = __float_as_uint(fmaf(-254.f, rc, MAGIC_C));
        }
        pk1 = (b[0] & 255u) | ((b[1] & 255u) << 8) | ((b[2] & 255u) << 16) | (b[3] << 24);
      }
      *(uint2*)(H + (cur ^ 1) * 8448 + chain * 528 + dbase + (kgrp << 3)) =
          make_uint2(pk0, pk1);
      // write next-step x (load issued ~a full step ago)
      {
        unsigned c0 = __float_as_uint(fminf(fmaxf(xv.x * SXQ, -127.f), 127.f) + MAGICF);
        unsigned c1 = __float_as_uint(fminf(fmaxf(xv.y * SXQ, -127.f), 127.f) + MAGICF);
        *(unsigned short*)(Xs + (cur ^ 1) * 2304 + wv * 144 + (lane << 1)) =
            (unsigned short)((c0 & 255u) | ((c1 & 255u) << 8));
      }
      asm volatile("s_waitcnt lgkmcnt(0)" ::: "memory");
      __builtin_amdgcn_s_barrier();
      __builtin_amdgcn_sched_barrier(0);
      cur ^= 1;
    }

    const int sid = meta[chain];
    const float s2 = -2.0f / (float)myLen;
    float* op = out + (size_t)sid * OUTW + DPROJ + dir * DLSTM + dbase + (kgrp << 3);
    *(float4*)op = make_float4(fmaf(s2, pool0[0], 1.f), fmaf(s2, pool0[1], 1.f),
                               fmaf(s2, pool0[2], 1.f), fmaf(s2, pool0[3], 1.f));
    *(float4*)(op + 4) = make_float4(fmaf(s2, pool1[0], 1.f), fmaf(s2, pool1[1], 1.f),
                                     fmaf(s2, pool1[2], 1.f), fmaf(s2, pool1[3], 1.f));
  }

  // ---------------- tail proj GEMM on the short-batch blocks ----------------
  if (bid >= 128) {
    const int pb = bid - 128;
    const int m0 = (pb >> 3) << 7, n0 = (pb & 7) << 7;
    unsigned short (*As)[40] = (unsigned short(*)[40])smem;              // [128][40]
    unsigned short (*Bs)[40] = (unsigned short(*)[40])(smem + 10240);    // [128][40]
    const int rowA = lane & 15, kgrp = lane >> 4;
    const int wm = (wv >> 2) << 5, wn = (wv & 3) << 5;
    const int srow = tid >> 3, skc = (tid & 7) << 2;

    f32x4 acc[2][2];
#pragma unroll
    for (int i = 0; i < 2; ++i)
#pragma unroll
      for (int j = 0; j < 2; ++j) acc[i][j] = (f32x4){0.f, 0.f, 0.f, 0.f};

    for (int k0 = 0; k0 < DX; k0 += 32) {
      __syncthreads();
      {
        float4 va = *(const float4*)(x + (size_t)(m0 + srow) * DX + k0 + skc);
        unsigned wa[2] = {cvtpk(va.x, va.y), cvtpk(va.z, va.w)};
        *(uint2*)&As[srow][skc] = *(uint2*)wa;
        float4 vb = *(const float4*)(Wx + (size_t)(n0 + srow) * DX + k0 + skc);
        unsigned wb2[2] = {cvtpk(vb.x, vb.y), cvtpk(vb.z, vb.w)};
        *(uint2*)&Bs[srow][skc] = *(uint2*)wb2;
      }
      __syncthreads();
      short8 af[2], bf[2];
#pragma unroll
      for (int mt = 0; mt < 2; ++mt) af[mt] = *(const short8*)&As[wm + mt * 16 + rowA][kgrp << 3];
#pragma unroll
      for (int nt = 0; nt < 2; ++nt) bf[nt] = *(const short8*)&Bs[wn + nt * 16 + rowA][kgrp << 3];
#pragma unroll
      for (int mt = 0; mt < 2; ++mt)
#pragma unroll
        for (int nt = 0; nt < 2; ++nt)
          acc[mt][nt] = __builtin_amdgcn_mfma_f32_16x16x32_bf16(af[mt], bf[nt], acc[mt][nt], 0, 0, 0);
    }

#pragma unroll
    for (int mt = 0; mt < 2; ++mt)
#pragma unroll
      for (int nt = 0; nt < 2; ++nt) {
        int n = n0 + wn + nt * 16 + rowA;
        float bv = bx[n];
#pragma unroll
        for (int r = 0; r < 4; ++r) {
          int m = m0 + wm + mt * 16 + (kgrp << 2) + r;
          out[(size_t)m * OUTW + n] = acc[mt][nt][r] + bv;
        }
      }
  }
}

extern "C" void kernel_launch(void* const* d_in, const int* in_sizes, int n_in,
                              void* d_out, int out_size, void* d_ws, size_t ws_size,
                              hipStream_t stream) {
  const float* x     = (const float*)d_in[0];
  const float* seqs  = (const float*)d_in[1];
  const int*   masks = (const int*)d_in[2];
  const float* Wih_f = (const float*)d_in[3];
  const float* Whh_f = (const float*)d_in[4];
  const float* b_f   = (const float*)d_in[5];
  const float* Wih_b = (const float*)d_in[6];
  const float* Whh_b = (const float*)d_in[7];
  const float* b_b   = (const float*)d_in[8];
  const float* Wx    = (const float*)d_in[9];
  const float* bx    = (const float*)d_in[10];
  float* out = (float*)d_out;

  char* ws = (char*)d_ws;
  signed char* W8  = (signed char*)ws;                        // 512 KB
  signed char* WX8 = (signed char*)(ws + (size_t)512 * 1024); // 128 KB
  int* s_sid = (int*)(ws + (size_t)640 * 1024);
  int* s_st  = s_sid + N_SEG;
  int* s_ln  = s_st + N_SEG;

  prep_kernel<<<41, 1024, 0, stream>>>(masks, Whh_f, Whh_b, Wih_f, Wih_b,
                                       W8, WX8, s_sid, s_st, s_ln);
  fused_kernel<<<256, 1024, 0, stream>>>(seqs, W8, WX8, s_sid, s_st, s_ln,
                                         b_f, b_b, x, Wx, bx, out);
}

// Round 10
// 80.514 us; speedup vs baseline: 1.1886x; 1.1181x over previous
//
#include <hip/hip_runtime.h>
#include <cstdint>
#include <cstddef>

#define T_N    32768
#define N_SEG  2048
#define DSEQ   128
#define DLSTM  512
#define DX     512
#define DPROJ  1024
#define OUTW   2048
#define WSCALE 2873.6827f                 // 127*sqrt(512)
#define SXQ    23.0909090909f             // 127/5.5 (x clip at +-5.5 sigma)
#define LOG2E2 2.8853900817779268f        // 2*log2(e)
#define DEQH   (2.8853900817779268f/(2873.6827f*127.0f))
#define DEQX   (2.8853900817779268f/(2873.6827f*23.0909090909f))
#define MAGICF 12582912.0f                // 1.5*2^23 RNE round-to-int trick
#define MAGIC_C (12582912.0f + 127.0f)

typedef __attribute__((ext_vector_type(8))) short short8;
typedef __attribute__((ext_vector_type(4))) float f32x4;
typedef __attribute__((ext_vector_type(4))) int i32x4;

#if __has_builtin(__builtin_amdgcn_exp2f)
#define EXP2F(x) __builtin_amdgcn_exp2f(x)
#else
#define EXP2F(x) __expf((x) * 0.6931471805599453f)
#endif
#if __has_builtin(__builtin_amdgcn_rcpf)
#define RCPF(x) __builtin_amdgcn_rcpf(x)
#else
#define RCPF(x) (1.0f / (x))
#endif

// opaque pin: keeps a loaded value register-resident (blocks load-sinking/remat)
#define PIN(x) asm volatile("" : "+v"(x))

__device__ inline unsigned int cvtpk(float a, float b) {
  unsigned int r;
  asm("v_cvt_pk_bf16_f32 %0, %1, %2" : "=v"(r) : "v"(a), "v"(b));
  return r;
}

// ================= launch 1: prep =================
// bid 0: seg bounds + counting sort (desc). bid 1..32: W_hh i8 frag pack.
// bid 33..40: W_ih i8 frag pack. 8-wave layout:
// W8  id = (((dir*8+wv)*4+mt)*8+kt)*64+lane ; WX8 id = (((dir*8+wv)*4+mt)*2+kt)*64+lane
// row perm: rr=lane&15 -> n = wv*64 + (rr>>2)*16 + mt*4 + (rr&3) ; k = kt*64+(lane>>4)*16+j
__global__ __launch_bounds__(1024) void prep_kernel(
    const int* __restrict__ masks,
    const float* __restrict__ Whh_f, const float* __restrict__ Whh_b,
    const float* __restrict__ Wih_f, const float* __restrict__ Wih_b,
    signed char* __restrict__ W8, signed char* __restrict__ WX8,
    int* __restrict__ s_sid, int* __restrict__ s_st, int* __restrict__ s_ln) {
  const int bid = blockIdx.x, tid = threadIdx.x;
  if (bid == 0) {
    __shared__ int st_l[2048], en_l[2048], A_[2048], B_[2048];
    for (int i = tid; i < 2048; i += 1024) A_[i] = 0;
    for (int t = tid; t < T_N; t += 1024) {
      int m = masks[t];
      if (t == 0 || masks[t - 1] != m) st_l[m] = t;
      if (t == T_N - 1 || masks[t + 1] != m) en_l[m] = t + 1;
    }
    __syncthreads();
    for (int i = tid; i < 2048; i += 1024) {
      int len = en_l[i] - st_l[i];
      atomicAdd(&A_[len < 2047 ? len : 2047], 1);
    }
    __syncthreads();
    int* src = A_;
    int* dst = B_;
    for (int d = 1; d < 2048; d <<= 1) {
      for (int i = tid; i < 2048; i += 1024) {
        int v = src[i];
        if (i + d < 2048) v += src[i + d];
        dst[i] = v;
      }
      __syncthreads();
      int* tp = src; src = dst; dst = tp;
    }
    for (int i = tid; i < 2048; i += 1024)
      dst[i] = (i + 1 < 2048) ? src[i + 1] : 0;
    __syncthreads();
    for (int i = tid; i < 2048; i += 1024) {
      int len = en_l[i] - st_l[i];
      int b = len < 2047 ? len : 2047;
      int pos = atomicAdd(&dst[b], 1);
      s_sid[pos] = i;
      s_st[pos] = st_l[i];
      s_ln[pos] = len;
    }
  } else if (bid <= 32) {
    int id = (bid - 1) * 1024 + tid;   // < 32768
    int lane = id & 63;
    int kt = (id >> 6) & 7;
    int mt = (id >> 9) & 3;
    int wv = (id >> 11) & 7;
    int dir = id >> 14;
    int rr = lane & 15;
    int n = wv * 64 + (rr >> 2) * 16 + mt * 4 + (rr & 3);
    int k0 = kt * 64 + (lane >> 4) * 16;
    const float* wp = (dir ? Whh_b : Whh_f) + (size_t)n * DLSTM + k0;
    signed char pkt[16];
#pragma unroll
    for (int q = 0; q < 4; ++q) {
      float4 v = *(const float4*)(wp + q * 4);
      float vv[4] = {v.x, v.y, v.z, v.w};
#pragma unroll
      for (int j = 0; j < 4; ++j) {
        int qq = (int)rintf(vv[j] * WSCALE);
        qq = qq > 127 ? 127 : (qq < -127 ? -127 : qq);
        pkt[q * 4 + j] = (signed char)qq;
      }
    }
    i32x4 v16;
    __builtin_memcpy(&v16, pkt, 16);
    *(i32x4*)&W8[(size_t)id * 16] = v16;
  } else {
    int id = (bid - 33) * 1024 + tid;  // < 8192
    int lane = id & 63;
    int kt = (id >> 6) & 1;
    int mt = (id >> 7) & 3;
    int wv = (id >> 9) & 7;
    int dir = id >> 12;
    int rr = lane & 15;
    int n = wv * 64 + (rr >> 2) * 16 + mt * 4 + (rr & 3);
    int k0 = kt * 64 + (lane >> 4) * 16;
    const float* wp = (dir ? Wih_b : Wih_f) + (size_t)n * DSEQ + k0;
    signed char pkt[16];
#pragma unroll
    for (int q = 0; q < 4; ++q) {
      float4 v = *(const float4*)(wp + q * 4);
      float vv[4] = {v.x, v.y, v.z, v.w};
#pragma unroll
      for (int j = 0; j < 4; ++j) {
        int qq = (int)rintf(vv[j] * WSCALE);
        qq = qq > 127 ? 127 : (qq < -127 ? -127 : qq);
        pkt[q * 4 + j] = (signed char)qq;
      }
    }
    i32x4 v16;
    __builtin_memcpy(&v16, pkt, 16);
    *(i32x4*)&WX8[(size_t)id * 16] = v16;
  }
}

// ================= launch 2: fused scan (+input proj) + tail proj GEMM =================
// grid 256, block 512 (8 waves, 2/SIMD, VGPR cap 256). Wave wv owns dims [wv*64, wv*64+64).
// Blocks >=128 (short batches) then do one 128x128 proj tile.
__global__ __launch_bounds__(512, 2) void fused_kernel(
    const float* __restrict__ seqs,
    const signed char* __restrict__ W8, const signed char* __restrict__ WX8,
    const int* __restrict__ s_sid_g, const int* __restrict__ s_st_g,
    const int* __restrict__ s_ln_g,
    const float* __restrict__ b_f, const float* __restrict__ b_b,
    const float* __restrict__ x, const float* __restrict__ Wx,
    const float* __restrict__ bx, float* __restrict__ out) {
  __shared__ __align__(16) char smem[21760];
  const int bid = blockIdx.x, tid = threadIdx.x;
  const int wv = tid >> 6, lane = tid & 63;

  // ---------------- scan phase ----------------
  {
    const int dir = bid & 1, bb = bid >> 1;
    const int chain = lane & 15, kgrp = lane >> 4;
    const int dbase = wv << 6;
    signed char* H = (signed char*)smem;             // [2][16][528]
    signed char* Xs = (signed char*)(smem + 16896);  // [2][16][144]
    int* meta = (int*)(smem + 21504);                // sid[16] | st[16] | ln[16]

    if (tid < 16) {
      meta[tid] = s_sid_g[bb * 16 + tid];
      meta[16 + tid] = s_st_g[bb * 16 + tid];
      meta[32 + tid] = s_ln_g[bb * 16 + tid];
    }
    {  // zero H[0]: 16 rows x 512B, 16B/thread
      int r = tid >> 5, o = (tid & 31) << 4;
      *(i32x4*)(H + r * 528 + o) = (i32x4){0, 0, 0, 0};
    }

    // register-resident weights: W_hh 32 frags (128 VGPR) + W_ih 8 frags (32 VGPR)
    i32x4 w[4][8], wx[4][2];
    {
      const signed char* wb = W8 + ((size_t)((dir << 3) + wv) << 15) + (lane << 4);
#pragma unroll
      for (int mt = 0; mt < 4; ++mt)
#pragma unroll
        for (int kt = 0; kt < 8; ++kt)
          w[mt][kt] = *(const i32x4*)(wb + (mt * 8 + kt) * 1024);
      const signed char* wxb = WX8 + ((size_t)((dir << 3) + wv) << 13) + (lane << 4);
#pragma unroll
      for (int mt = 0; mt < 4; ++mt)
#pragma unroll
        for (int kt = 0; kt < 2; ++kt)
          wx[mt][kt] = *(const i32x4*)(wxb + (mt * 2 + kt) * 1024);
    }
    // pin: make values opaque so loads can't be sunk into the loop
#pragma unroll
    for (int mt = 0; mt < 4; ++mt) {
#pragma unroll
      for (int kt = 0; kt < 8; ++kt) PIN(w[mt][kt]);
      PIN(wx[mt][0]); PIN(wx[mt][1]);
    }

    float bsc[16];
    {
      const float* bp = (dir ? b_b : b_f) + dbase + (kgrp << 4);
#pragma unroll
      for (int mt = 0; mt < 4; ++mt) {
        float4 u = *(const float4*)(bp + mt * 4);
        bsc[mt * 4 + 0] = u.x * LOG2E2; bsc[mt * 4 + 1] = u.y * LOG2E2;
        bsc[mt * 4 + 2] = u.z * LOG2E2; bsc[mt * 4 + 3] = u.w * LOG2E2;
      }
    }
    __syncthreads();

    const int myLen = meta[32 + chain];
    const int csn = (wv << 1) + (lane >> 5);           // chain this thread stages
    const int stStart = meta[16 + csn], stLen = meta[32 + csn];
    const int maxlen = meta[32];                       // sorted desc -> batch max
    const int jx = (lane & 31) << 2;                   // 4 floats of seq row

    // prologue: stage x(0)
    {
      int t0 = dir ? (stStart + stLen - 1) : stStart;
      float4 xv0 = *(const float4*)(seqs + (size_t)t0 * DSEQ + jx);
      unsigned c0 = __float_as_uint(fminf(fmaxf(xv0.x * SXQ, -127.f), 127.f) + MAGICF);
      unsigned c1 = __float_as_uint(fminf(fmaxf(xv0.y * SXQ, -127.f), 127.f) + MAGICF);
      unsigned c2 = __float_as_uint(fminf(fmaxf(xv0.z * SXQ, -127.f), 127.f) + MAGICF);
      unsigned c3 = __float_as_uint(fminf(fmaxf(xv0.w * SXQ, -127.f), 127.f) + MAGICF);
      *(unsigned*)(Xs + csn * 144 + jx) =
          (c0 & 255u) | ((c1 & 255u) << 8) | ((c2 & 255u) << 16) | ((c3 & 255u) << 24);
    }
    __syncthreads();

    float pool[4][4];
#pragma unroll
    for (int mt = 0; mt < 4; ++mt)
#pragma unroll
      for (int r = 0; r < 4; ++r) pool[mt][r] = 0.f;

    int cur = 0;
    for (int s = 0; s < maxlen; ++s) {
      // issue next-step x load early (consumed at bottom of this body)
      int sn = (s + 1 < stLen) ? (s + 1) : (stLen - 1);
      int tn = dir ? (stStart + stLen - 1 - sn) : (stStart + sn);
      float4 xv = *(const float4*)(seqs + (size_t)tn * DSEQ + jx);

      i32x4 acc[4], ax[4];
#pragma unroll
      for (int mt = 0; mt < 4; ++mt) {
        acc[mt] = (i32x4){0, 0, 0, 0};
        ax[mt] = (i32x4){0, 0, 0, 0};
      }
      {
        const signed char* xr = Xs + cur * 2304 + chain * 144;
#pragma unroll
        for (int kt = 0; kt < 2; ++kt) {
          i32x4 xb = *(const i32x4*)(xr + kt * 64 + (kgrp << 4));
#pragma unroll
          for (int mt = 0; mt < 4; ++mt)
            ax[mt] = __builtin_amdgcn_mfma_i32_16x16x64_i8(wx[mt][kt], xb, ax[mt], 0, 0, 0);
        }
        const signed char* hr = H + cur * 8448 + chain * 528;
#pragma unroll
        for (int kt = 0; kt < 8; ++kt) {
          i32x4 hb = *(const i32x4*)(hr + kt * 64 + (kgrp << 4));
#pragma unroll
          for (int mt = 0; mt < 4; ++mt)
            acc[mt] = __builtin_amdgcn_mfma_i32_16x16x64_i8(w[mt][kt], hb, acc[mt], 0, 0, 0);
        }
      }

      const float msk = (s < myLen) ? 1.f : 0.f;
      unsigned hw[4];
#pragma unroll
      for (int mt = 0; mt < 4; ++mt) {
        unsigned b[4];
#pragma unroll
        for (int r = 0; r < 4; ++r) {
          float x2 = fmaf((float)acc[mt][r], DEQH,
                          fmaf((float)ax[mt][r], DEQX, bsc[mt * 4 + r]));
          float e = EXP2F(x2);
          float rc = RCPF(e + 1.f);
          pool[mt][r] = fmaf(rc, msk, pool[mt][r]);
          b[r] = __float_as_uint(fmaf(-254.f, rc, MAGIC_C));
        }
        hw[mt] = (b[0] & 255u) | ((b[1] & 255u) << 8) | ((b[2] & 255u) << 16) | (b[3] << 24);
      }
      // one 16B write: dims dbase+kgrp*16 .. +15 of this chain
      *(uint4*)(H + (cur ^ 1) * 8448 + chain * 528 + dbase + (kgrp << 4)) =
          make_uint4(hw[0], hw[1], hw[2], hw[3]);
      // write next-step x (load issued a full phase ago)
      {
        unsigned c0 = __float_as_uint(fminf(fmaxf(xv.x * SXQ, -127.f), 127.f) + MAGICF);
        unsigned c1 = __float_as_uint(fminf(fmaxf(xv.y * SXQ, -127.f), 127.f) + MAGICF);
        unsigned c2 = __float_as_uint(fminf(fmaxf(xv.z * SXQ, -127.f), 127.f) + MAGICF);
        unsigned c3 = __float_as_uint(fminf(fmaxf(xv.w * SXQ, -127.f), 127.f) + MAGICF);
        *(unsigned*)(Xs + (cur ^ 1) * 2304 + csn * 144 + jx) =
            (c0 & 255u) | ((c1 & 255u) << 8) | ((c2 & 255u) << 16) | ((c3 & 255u) << 24);
      }
      asm volatile("s_waitcnt lgkmcnt(0)" ::: "memory");
      __builtin_amdgcn_s_barrier();
      __builtin_amdgcn_sched_barrier(0);
      cur ^= 1;
    }

    const int sid = meta[chain];
    const float s2 = -2.0f / (float)myLen;
    float* op = out + (size_t)sid * OUTW + DPROJ + dir * DLSTM + dbase + (kgrp << 4);
#pragma unroll
    for (int mt = 0; mt < 4; ++mt)
      *(float4*)(op + mt * 4) =
          make_float4(fmaf(s2, pool[mt][0], 1.f), fmaf(s2, pool[mt][1], 1.f),
                      fmaf(s2, pool[mt][2], 1.f), fmaf(s2, pool[mt][3], 1.f));
  }

  // ---------------- tail proj GEMM on the short-batch blocks ----------------
  if (bid >= 128) {
    const int pb = bid - 128;
    const int m0 = (pb >> 3) << 7, n0 = (pb & 7) << 7;
    unsigned short (*As)[40] = (unsigned short(*)[40])smem;              // [128][40]
    unsigned short (*Bs)[40] = (unsigned short(*)[40])(smem + 10240);    // [128][40]
    const int rowA = lane & 15, kgrp = lane >> 4;
    const int wm = (wv & 1) << 6, wn = (wv >> 1) << 5;
    const int srow = tid >> 2, skc = (tid & 3) << 3;

    f32x4 acc[4][2];
#pragma unroll
    for (int i = 0; i < 4; ++i)
#pragma unroll
      for (int j = 0; j < 2; ++j) acc[i][j] = (f32x4){0.f, 0.f, 0.f, 0.f};

    for (int k0 = 0; k0 < DX; k0 += 32) {
      __syncthreads();
      {
        const float* ap = x + (size_t)(m0 + srow) * DX + k0 + skc;
        float4 va0 = *(const float4*)ap;
        float4 va1 = *(const float4*)(ap + 4);
        unsigned wa[4] = {cvtpk(va0.x, va0.y), cvtpk(va0.z, va0.w),
                          cvtpk(va1.x, va1.y), cvtpk(va1.z, va1.w)};
        *(uint4*)&As[srow][skc] = *(uint4*)wa;
        const float* bp = Wx + (size_t)(n0 + srow) * DX + k0 + skc;
        float4 vb0 = *(const float4*)bp;
        float4 vb1 = *(const float4*)(bp + 4);
        unsigned wb2[4] = {cvtpk(vb0.x, vb0.y), cvtpk(vb0.z, vb0.w),
                           cvtpk(vb1.x, vb1.y), cvtpk(vb1.z, vb1.w)};
        *(uint4*)&Bs[srow][skc] = *(uint4*)wb2;
      }
      __syncthreads();
      short8 af[4], bf[2];
#pragma unroll
      for (int mt = 0; mt < 4; ++mt)
        af[mt] = *(const short8*)&As[wm + mt * 16 + rowA][kgrp << 3];
#pragma unroll
      for (int nt = 0; nt < 2; ++nt)
        bf[nt] = *(const short8*)&Bs[wn + nt * 16 + rowA][kgrp << 3];
#pragma unroll
      for (int mt = 0; mt < 4; ++mt)
#pragma unroll
        for (int nt = 0; nt < 2; ++nt)
          acc[mt][nt] = __builtin_amdgcn_mfma_f32_16x16x32_bf16(af[mt], bf[nt], acc[mt][nt], 0, 0, 0);
    }

#pragma unroll
    for (int mt = 0; mt < 4; ++mt)
#pragma unroll
      for (int nt = 0; nt < 2; ++nt) {
        int n = n0 + wn + nt * 16 + rowA;
        float bv = bx[n];
#pragma unroll
        for (int r = 0; r < 4; ++r) {
          int m = m0 + wm + mt * 16 + (kgrp << 2) + r;
          out[(size_t)m * OUTW + n] = acc[mt][nt][r] + bv;
        }
      }
  }
}

extern "C" void kernel_launch(void* const* d_in, const int* in_sizes, int n_in,
                              void* d_out, int out_size, void* d_ws, size_t ws_size,
                              hipStream_t stream) {
  const float* x     = (const float*)d_in[0];
  const float* seqs  = (const float*)d_in[1];
  const int*   masks = (const int*)d_in[2];
  const float* Wih_f = (const float*)d_in[3];
  const float* Whh_f = (const float*)d_in[4];
  const float* b_f   = (const float*)d_in[5];
  const float* Wih_b = (const float*)d_in[6];
  const float* Whh_b = (const float*)d_in[7];
  const float* b_b   = (const float*)d_in[8];
  const float* Wx    = (const float*)d_in[9];
  const float* bx    = (const float*)d_in[10];
  float* out = (float*)d_out;

  char* ws = (char*)d_ws;
  signed char* W8  = (signed char*)ws;                        // 512 KB
  signed char* WX8 = (signed char*)(ws + (size_t)512 * 1024); // 128 KB
  int* s_sid = (int*)(ws + (size_t)640 * 1024);
  int* s_st  = s_sid + N_SEG;
  int* s_ln  = s_st + N_SEG;

  prep_kernel<<<41, 1024, 0, stream>>>(masks, Whh_f, Whh_b, Wih_f, Wih_b,
                                       W8, WX8, s_sid, s_st, s_ln);
  fused_kernel<<<256, 512, 0, stream>>>(seqs, W8, WX8, s_sid, s_st, s_ln,
                                        b_f, b_b, x, Wx, bx, out);
}

// Round 11
// 63.073 us; speedup vs baseline: 1.5173x; 1.2765x over previous
//
#include <hip/hip_runtime.h>
#include <cstdint>
#include <cstddef>

#define T_N    32768
#define N_SEG  2048
#define DSEQ   128
#define DLSTM  512
#define DX     512
#define DPROJ  1024
#define OUTW   2048
#define WSCALE 2873.6827f                 // 127*sqrt(512)
#define SXQ    15.875f                    // 127/8: DEQX = 8*DEQH (integer fold)
#define LOG2E2 2.8853900817779268f        // 2*log2(e)
#define DEQH   (2.8853900817779268f/(2873.6827f*127.0f))
#define MAGICF 12582912.0f                // 1.5*2^23 RNE round-to-int trick
#define MAGIC_C (12582912.0f + 127.0f)

typedef __attribute__((ext_vector_type(8))) short short8;
typedef __attribute__((ext_vector_type(4))) float f32x4;
typedef __attribute__((ext_vector_type(4))) int i32x4;

#if __has_builtin(__builtin_amdgcn_exp2f)
#define EXP2F(x) __builtin_amdgcn_exp2f(x)
#else
#define EXP2F(x) __expf((x) * 0.6931471805599453f)
#endif
#if __has_builtin(__builtin_amdgcn_rcpf)
#define RCPF(x) __builtin_amdgcn_rcpf(x)
#else
#define RCPF(x) (1.0f / (x))
#endif

// opaque pin: keeps loaded values register-resident (blocks load-sinking/remat)
#define PIN(x) asm volatile("" : "+v"(x))

__device__ inline unsigned int cvtpk(float a, float b) {
  unsigned int r;
  asm("v_cvt_pk_bf16_f32 %0, %1, %2" : "=v"(r) : "v"(a), "v"(b));
  return r;
}

// ================= launch 1: prep (fully parallel, 256-thr blocks) =================
// bid [0,128): seg bounds. bid [128,256): W_hh i8 frag pack. bid [256,288): W_ih pack.
// W8  id = (((dir*8+wv)*4+mt)*8+kt)*64+lane ; WX8 id = (((dir*8+wv)*4+mt)*2+kt)*64+lane
// row perm: rr=lane&15 -> n = wv*64 + (rr>>2)*16 + mt*4 + (rr&3) ; k = kt*64+(lane>>4)*16+j
__global__ __launch_bounds__(256) void prep_kernel(
    const int* __restrict__ masks,
    const float* __restrict__ Whh_f, const float* __restrict__ Whh_b,
    const float* __restrict__ Wih_f, const float* __restrict__ Wih_b,
    signed char* __restrict__ W8, signed char* __restrict__ WX8,
    int* __restrict__ seg_start, int* __restrict__ seg_end,
    int* __restrict__ tile_ctr) {
  const int bid = blockIdx.x, tid = threadIdx.x;
  if (bid == 0 && tid == 0) *tile_ctr = 0;
  if (bid < 128) {
    int t = bid * 256 + tid;
    int m = masks[t];
    if (t == 0 || masks[t - 1] != m) seg_start[m] = t;
    if (t == T_N - 1 || masks[t + 1] != m) seg_end[m] = t + 1;
  } else if (bid < 256) {
    int id = (bid - 128) * 256 + tid;   // < 32768
    int lane = id & 63;
    int kt = (id >> 6) & 7;
    int mt = (id >> 9) & 3;
    int wv = (id >> 11) & 7;
    int dir = id >> 14;
    int rr = lane & 15;
    int n = wv * 64 + (rr >> 2) * 16 + mt * 4 + (rr & 3);
    int k0 = kt * 64 + (lane >> 4) * 16;
    const float* wp = (dir ? Whh_b : Whh_f) + (size_t)n * DLSTM + k0;
    signed char pkt[16];
#pragma unroll
    for (int q = 0; q < 4; ++q) {
      float4 v = *(const float4*)(wp + q * 4);
      float vv[4] = {v.x, v.y, v.z, v.w};
#pragma unroll
      for (int j = 0; j < 4; ++j) {
        int qq = (int)rintf(vv[j] * WSCALE);
        qq = qq > 127 ? 127 : (qq < -127 ? -127 : qq);
        pkt[q * 4 + j] = (signed char)qq;
      }
    }
    i32x4 v16;
    __builtin_memcpy(&v16, pkt, 16);
    *(i32x4*)&W8[(size_t)id * 16] = v16;
  } else {
    int id = (bid - 256) * 256 + tid;  // < 8192
    int lane = id & 63;
    int kt = (id >> 6) & 1;
    int mt = (id >> 7) & 3;
    int wv = (id >> 9) & 7;
    int dir = id >> 12;
    int rr = lane & 15;
    int n = wv * 64 + (rr >> 2) * 16 + mt * 4 + (rr & 3);
    int k0 = kt * 64 + (lane >> 4) * 16;
    const float* wp = (dir ? Wih_b : Wih_f) + (size_t)n * DSEQ + k0;
    signed char pkt[16];
#pragma unroll
    for (int q = 0; q < 4; ++q) {
      float4 v = *(const float4*)(wp + q * 4);
      float vv[4] = {v.x, v.y, v.z, v.w};
#pragma unroll
      for (int j = 0; j < 4; ++j) {
        int qq = (int)rintf(vv[j] * SXQ * WSCALE / SXQ);  // = WSCALE (kept explicit)
        qq = qq > 127 ? 127 : (qq < -127 ? -127 : qq);
        pkt[q * 4 + j] = (signed char)qq;
      }
    }
    i32x4 v16;
    __builtin_memcpy(&v16, pkt, 16);
    *(i32x4*)&WX8[(size_t)id * 16] = v16;
  }
}

// ================= launch 2: fused scan (+input proj) + queued proj GEMM =================
// grid 256, block 512 (8 waves). Block bid: batch = bid>>1 (chains bb*16..+15), dir = bid&1.
// After the scan, blocks pull 128x128 proj tiles from a global queue.
__global__ __launch_bounds__(512, 2) void fused_kernel(
    const float* __restrict__ seqs,
    const signed char* __restrict__ W8, const signed char* __restrict__ WX8,
    const int* __restrict__ seg_start, const int* __restrict__ seg_end,
    const float* __restrict__ b_f, const float* __restrict__ b_b,
    const float* __restrict__ x, const float* __restrict__ Wx,
    const float* __restrict__ bx, float* __restrict__ out,
    int* __restrict__ tile_ctr) {
  __shared__ __align__(16) char smem[21760];
  const int bid = blockIdx.x, tid = threadIdx.x;
  const int wv = tid >> 6, lane = tid & 63;

  // ---------------- scan phase ----------------
  {
    const int dir = bid & 1, bb = bid >> 1;
    const int chain = lane & 15, kgrp = lane >> 4;
    const int dbase = wv << 6;
    signed char* H = (signed char*)smem;             // [2][16][528]
    signed char* Xs = (signed char*)(smem + 16896);  // [2][16][144]
    int* meta = (int*)(smem + 21504);                // st[16] | ln[16]

    if (tid < 16) {
      int st = seg_start[bb * 16 + tid];
      meta[tid] = st;
      meta[16 + tid] = seg_end[bb * 16 + tid] - st;
    }
    {  // zero H[0]: 16 rows x 512B, 16B/thread
      int r = tid >> 5, o = (tid & 31) << 4;
      *(i32x4*)(H + r * 528 + o) = (i32x4){0, 0, 0, 0};
    }

    // register-resident weights: W_hh 32 frags (128 regs) + W_ih 8 frags (32 regs)
    i32x4 w[4][8], wx[4][2];
    {
      const signed char* wb = W8 + ((size_t)((dir << 3) + wv) << 15) + (lane << 4);
#pragma unroll
      for (int mt = 0; mt < 4; ++mt)
#pragma unroll
        for (int kt = 0; kt < 8; ++kt)
          w[mt][kt] = *(const i32x4*)(wb + (mt * 8 + kt) * 1024);
      const signed char* wxb = WX8 + ((size_t)((dir << 3) + wv) << 13) + (lane << 4);
#pragma unroll
      for (int mt = 0; mt < 4; ++mt)
#pragma unroll
        for (int kt = 0; kt < 2; ++kt)
          wx[mt][kt] = *(const i32x4*)(wxb + (mt * 2 + kt) * 1024);
    }
#pragma unroll
    for (int mt = 0; mt < 4; ++mt) {
#pragma unroll
      for (int kt = 0; kt < 8; ++kt) PIN(w[mt][kt]);
      PIN(wx[mt][0]); PIN(wx[mt][1]);
    }

    float bsc[16];
    {
      const float* bp = (dir ? b_b : b_f) + dbase + (kgrp << 4);
#pragma unroll
      for (int mt = 0; mt < 4; ++mt) {
        float4 u = *(const float4*)(bp + mt * 4);
        bsc[mt * 4 + 0] = u.x * LOG2E2; bsc[mt * 4 + 1] = u.y * LOG2E2;
        bsc[mt * 4 + 2] = u.z * LOG2E2; bsc[mt * 4 + 3] = u.w * LOG2E2;
      }
    }
    __syncthreads();

    int maxlen = 0;
#pragma unroll
    for (int c = 0; c < 16; ++c) {
      int l = meta[16 + c];
      maxlen = maxlen > l ? maxlen : l;
    }
    const int myLen = meta[16 + chain];
    const int csn = (wv << 1) + (lane >> 5);           // chain this thread stages
    const int stStart = meta[csn], stLen = meta[16 + csn];
    const int jx = (lane & 31) << 2;                   // 4 floats of seq row

    // prologue: stage x(0)
    {
      int t0 = dir ? (stStart + stLen - 1) : stStart;
      float4 xv0 = *(const float4*)(seqs + (size_t)t0 * DSEQ + jx);
      unsigned c0 = __float_as_uint(fminf(fmaxf(xv0.x * SXQ, -127.f), 127.f) + MAGICF);
      unsigned c1 = __float_as_uint(fminf(fmaxf(xv0.y * SXQ, -127.f), 127.f) + MAGICF);
      unsigned c2 = __float_as_uint(fminf(fmaxf(xv0.z * SXQ, -127.f), 127.f) + MAGICF);
      unsigned c3 = __float_as_uint(fminf(fmaxf(xv0.w * SXQ, -127.f), 127.f) + MAGICF);
      *(unsigned*)(Xs + csn * 144 + jx) =
          (c0 & 255u) | ((c1 & 255u) << 8) | ((c2 & 255u) << 16) | ((c3 & 255u) << 24);
    }
    __syncthreads();

    float pool[4][4];
#pragma unroll
    for (int mt = 0; mt < 4; ++mt)
#pragma unroll
      for (int r = 0; r < 4; ++r) pool[mt][r] = 0.f;

    int cur = 0;
    for (int s = 0; s < maxlen; ++s) {
      // issue next-step x load early (consumed at bottom of this body)
      int sn = (s + 1 < stLen) ? (s + 1) : (stLen - 1);
      int tn = dir ? (stStart + stLen - 1 - sn) : (stStart + sn);
      float4 xv = *(const float4*)(seqs + (size_t)tn * DSEQ + jx);

      i32x4 acc[4], ax[4];
#pragma unroll
      for (int mt = 0; mt < 4; ++mt) {
        acc[mt] = (i32x4){0, 0, 0, 0};
        ax[mt] = (i32x4){0, 0, 0, 0};
      }
      {
        const signed char* xr = Xs + cur * 2304 + chain * 144;
#pragma unroll
        for (int kt = 0; kt < 2; ++kt) {
          i32x4 xb = *(const i32x4*)(xr + kt * 64 + (kgrp << 4));
#pragma unroll
          for (int mt = 0; mt < 4; ++mt)
            ax[mt] = __builtin_amdgcn_mfma_i32_16x16x64_i8(wx[mt][kt], xb, ax[mt], 0, 0, 0);
        }
        const signed char* hr = H + cur * 8448 + chain * 528;
        __builtin_amdgcn_s_setprio(1);
#pragma unroll
        for (int kt = 0; kt < 8; ++kt) {
          i32x4 hb = *(const i32x4*)(hr + kt * 64 + (kgrp << 4));
#pragma unroll
          for (int mt = 0; mt < 4; ++mt)
            acc[mt] = __builtin_amdgcn_mfma_i32_16x16x64_i8(w[mt][kt], hb, acc[mt], 0, 0, 0);
        }
        __builtin_amdgcn_s_setprio(0);
      }

      const float msk = (s < myLen) ? 1.f : 0.f;
      unsigned hw[4];
#pragma unroll
      for (int mt = 0; mt < 4; ++mt) {
        unsigned b[4];
#pragma unroll
        for (int r = 0; r < 4; ++r) {
          int comb = acc[mt][r] + (ax[mt][r] << 3);     // DEQX = 8*DEQH
          float x2 = fmaf((float)comb, DEQH, bsc[mt * 4 + r]);
          float e = EXP2F(x2);
          float rc = RCPF(e + 1.f);
          pool[mt][r] = fmaf(rc, msk, pool[mt][r]);
          b[r] = __float_as_uint(fmaf(-254.f, rc, MAGIC_C));
        }
        hw[mt] = (b[0] & 255u) | ((b[1] & 255u) << 8) | ((b[2] & 255u) << 16) | (b[3] << 24);
      }
      *(uint4*)(H + (cur ^ 1) * 8448 + chain * 528 + dbase + (kgrp << 4)) =
          make_uint4(hw[0], hw[1], hw[2], hw[3]);
      // write next-step x (load issued a full phase ago)
      {
        unsigned c0 = __float_as_uint(fminf(fmaxf(xv.x * SXQ, -127.f), 127.f) + MAGICF);
        unsigned c1 = __float_as_uint(fminf(fmaxf(xv.y * SXQ, -127.f), 127.f) + MAGICF);
        unsigned c2 = __float_as_uint(fminf(fmaxf(xv.z * SXQ, -127.f), 127.f) + MAGICF);
        unsigned c3 = __float_as_uint(fminf(fmaxf(xv.w * SXQ, -127.f), 127.f) + MAGICF);
        *(unsigned*)(Xs + (cur ^ 1) * 2304 + csn * 144 + jx) =
            (c0 & 255u) | ((c1 & 255u) << 8) | ((c2 & 255u) << 16) | ((c3 & 255u) << 24);
      }
      asm volatile("s_waitcnt lgkmcnt(0)" ::: "memory");
      __builtin_amdgcn_s_barrier();
      __builtin_amdgcn_sched_barrier(0);
      cur ^= 1;
    }

    const int sid = bb * 16 + chain;
    const float s2 = -2.0f / (float)myLen;
    float* op = out + (size_t)sid * OUTW + DPROJ + dir * DLSTM + dbase + (kgrp << 4);
#pragma unroll
    for (int mt = 0; mt < 4; ++mt)
      *(float4*)(op + mt * 4) =
          make_float4(fmaf(s2, pool[mt][0], 1.f), fmaf(s2, pool[mt][1], 1.f),
                      fmaf(s2, pool[mt][2], 1.f), fmaf(s2, pool[mt][3], 1.f));
  }

  // ---------------- queued proj GEMM: blocks pull 128x128 tiles as they free up ----------------
  {
    int* tileslot = (int*)(smem + 21632);
    unsigned short (*As)[40] = (unsigned short(*)[40])smem;              // [128][40]
    unsigned short (*Bs)[40] = (unsigned short(*)[40])(smem + 10240);    // [128][40]
    const int rowA = lane & 15, kgrp = lane >> 4;
    const int wm = (wv & 1) << 6, wn = (wv >> 1) << 5;
    const int srow = tid >> 2, skc = (tid & 3) << 3;

    for (;;) {
      __syncthreads();   // smem quiescent (scan done / previous tile done)
      if (tid == 0) *tileslot = atomicAdd(tile_ctr, 1);
      __syncthreads();
      const int tile = *tileslot;
      if (tile >= 128) break;
      const int m0 = (tile >> 3) << 7, n0 = (tile & 7) << 7;

      f32x4 acc[4][2];
#pragma unroll
      for (int i = 0; i < 4; ++i)
#pragma unroll
        for (int j = 0; j < 2; ++j) acc[i][j] = (f32x4){0.f, 0.f, 0.f, 0.f};

      for (int k0 = 0; k0 < DX; k0 += 32) {
        __syncthreads();
        {
          const float* ap = x + (size_t)(m0 + srow) * DX + k0 + skc;
          float4 va0 = *(const float4*)ap;
          float4 va1 = *(const float4*)(ap + 4);
          unsigned wa[4] = {cvtpk(va0.x, va0.y), cvtpk(va0.z, va0.w),
                            cvtpk(va1.x, va1.y), cvtpk(va1.z, va1.w)};
          *(uint4*)&As[srow][skc] = *(uint4*)wa;
          const float* bp = Wx + (size_t)(n0 + srow) * DX + k0 + skc;
          float4 vb0 = *(const float4*)bp;
          float4 vb1 = *(const float4*)(bp + 4);
          unsigned wb2[4] = {cvtpk(vb0.x, vb0.y), cvtpk(vb0.z, vb0.w),
                             cvtpk(vb1.x, vb1.y), cvtpk(vb1.z, vb1.w)};
          *(uint4*)&Bs[srow][skc] = *(uint4*)wb2;
        }
        __syncthreads();
        short8 af[4], bf[2];
#pragma unroll
        for (int mt = 0; mt < 4; ++mt)
          af[mt] = *(const short8*)&As[wm + mt * 16 + rowA][kgrp << 3];
#pragma unroll
        for (int nt = 0; nt < 2; ++nt)
          bf[nt] = *(const short8*)&Bs[wn + nt * 16 + rowA][kgrp << 3];
#pragma unroll
        for (int mt = 0; mt < 4; ++mt)
#pragma unroll
          for (int nt = 0; nt < 2; ++nt)
            acc[mt][nt] = __builtin_amdgcn_mfma_f32_16x16x32_bf16(af[mt], bf[nt], acc[mt][nt], 0, 0, 0);
      }

#pragma unroll
      for (int mt = 0; mt < 4; ++mt)
#pragma unroll
        for (int nt = 0; nt < 2; ++nt) {
          int n = n0 + wn + nt * 16 + rowA;
          float bv = bx[n];
#pragma unroll
          for (int r = 0; r < 4; ++r) {
            int m = m0 + wm + mt * 16 + (kgrp << 2) + r;
            out[(size_t)m * OUTW + n] = acc[mt][nt][r] + bv;
          }
        }
    }
  }
}

extern "C" void kernel_launch(void* const* d_in, const int* in_sizes, int n_in,
                              void* d_out, int out_size, void* d_ws, size_t ws_size,
                              hipStream_t stream) {
  const float* x     = (const float*)d_in[0];
  const float* seqs  = (const float*)d_in[1];
  const int*   masks = (const int*)d_in[2];
  const float* Wih_f = (const float*)d_in[3];
  const float* Whh_f = (const float*)d_in[4];
  const float* b_f   = (const float*)d_in[5];
  const float* Wih_b = (const float*)d_in[6];
  const float* Whh_b = (const float*)d_in[7];
  const float* b_b   = (const float*)d_in[8];
  const float* Wx    = (const float*)d_in[9];
  const float* bx    = (const float*)d_in[10];
  float* out = (float*)d_out;

  char* ws = (char*)d_ws;
  signed char* W8  = (signed char*)ws;                        // 512 KB
  signed char* WX8 = (signed char*)(ws + (size_t)512 * 1024); // 128 KB
  int* seg_start = (int*)(ws + (size_t)640 * 1024);
  int* seg_end   = seg_start + N_SEG;
  int* tile_ctr  = seg_end + N_SEG;

  prep_kernel<<<288, 256, 0, stream>>>(masks, Whh_f, Whh_b, Wih_f, Wih_b,
                                       W8, WX8, seg_start, seg_end, tile_ctr);
  fused_kernel<<<256, 512, 0, stream>>>(seqs, W8, WX8, seg_start, seg_end,
                                        b_f, b_b, x, Wx, bx, out, tile_ctr);
}